// Round 1
// baseline (255.567 us; speedup 1.0000x reference)
//
#include <hip/hip_runtime.h>
#include <math.h>

#define DEG 32
#define IN_F 64
#define NHO 64  // HEADS*OUT_F = 4*16

// ---------------------------------------------------------------------------
// Projection: P[n][l] = sum_i W[l][i] * Q[i][n]   for l = h*16+o in [0,64)
// W is [64][64] row-major ((h*O+o)*IN_F + i). Q is [IN_F][N].
// blockIdx.y selects (query_weight -> Pq) or (key_weight -> Pk).
// Weights staged transposed in LDS so the inner loop reads contiguous float4.
// ---------------------------------------------------------------------------
__global__ __launch_bounds__(256) void proj_kernel(
    const float* __restrict__ Q,
    const float* __restrict__ Wq,
    const float* __restrict__ Wk,
    float* __restrict__ Pq,
    float* __restrict__ Pk,
    int N)
{
    __shared__ float wt[64 * 64];  // wt[i*64 + l] = W[l*64 + i]
    const float* W = (blockIdx.y == 0) ? Wq : Wk;
    float*       P = (blockIdx.y == 0) ? Pq : Pk;

    int t = threadIdx.x;
    for (int idx = t; idx < 64 * 64; idx += 256) {
        int l = idx >> 6, i = idx & 63;
        wt[i * 64 + l] = W[idx];
    }
    __syncthreads();

    int n = blockIdx.x * 256 + t;
    if (n >= N) return;

    float acc[64];
#pragma unroll
    for (int l = 0; l < 64; l++) acc[l] = 0.f;

    for (int i = 0; i < 64; i++) {
        float qv = Q[(size_t)i * N + n];  // coalesced across threads
        const float4* w4 = (const float4*)&wt[i * 64];
#pragma unroll
        for (int l4 = 0; l4 < 16; l4++) {
            float4 w = w4[l4];  // LDS broadcast (same addr all lanes)
            acc[4 * l4 + 0] = fmaf(w.x, qv, acc[4 * l4 + 0]);
            acc[4 * l4 + 1] = fmaf(w.y, qv, acc[4 * l4 + 1]);
            acc[4 * l4 + 2] = fmaf(w.z, qv, acc[4 * l4 + 2]);
            acc[4 * l4 + 3] = fmaf(w.w, qv, acc[4 * l4 + 3]);
        }
    }

    float4* p4 = (float4*)&P[(size_t)n * 64];
#pragma unroll
    for (int l4 = 0; l4 < 16; l4++)
        p4[l4] = make_float4(acc[4 * l4], acc[4 * l4 + 1],
                             acc[4 * l4 + 2], acc[4 * l4 + 3]);
}

// ---------------------------------------------------------------------------
// Main GAT kernel: one wave (64 lanes) per node; lane = h*16 + o.
// Phase 1: per neighbor k, coalesced 256B gather of Pk[j], butterfly-reduce
//          the attention logit over the 16 o-lanes of each head.
// Phase 2: register-only masked softmax + weighted aggregation.
// ---------------------------------------------------------------------------
__global__ __launch_bounds__(256) void gat_kernel(
    const int*   __restrict__ adj,   // [N][DEG]
    const float* __restrict__ Pq,    // [N][64]
    const float* __restrict__ Pk,    // [N][64]
    const float* __restrict__ aw,    // [64]  (h*16+o)
    float*       __restrict__ out,   // [64][N]
    int N)
{
    int lane = threadIdx.x & 63;
    int wv   = threadIdx.x >> 6;
    int n    = blockIdx.x * 4 + wv;
    if (n >= N) return;

    float a  = aw[lane];
    float qv = Pq[(size_t)n * 64 + lane];

    int jreg = -1;
    if (lane < DEG) jreg = adj[(size_t)n * DEG + lane];  // coalesced 128B

    float logit[DEG];
    float kvv[DEG];
    float m = -INFINITY;

#pragma unroll
    for (int k = 0; k < DEG; k++) {
        int j = __shfl(jreg, k, 64);   // wave-uniform neighbor id
        float kv = 0.f, lg = -INFINITY;
        if (j >= 0) {
            kv = Pk[(size_t)j * 64 + lane];  // coalesced 256B gather
            float x = qv + kv;
            x = (x > 0.f) ? x : 0.01f * x;   // leaky_relu
            float c = a * x;
            // sum over the 16 o-lanes of this head (butterfly -> all lanes)
            c += __shfl_xor(c, 1, 16);
            c += __shfl_xor(c, 2, 16);
            c += __shfl_xor(c, 4, 16);
            c += __shfl_xor(c, 8, 16);
            lg = c;
            m = fmaxf(m, c);
        }
        logit[k] = lg;
        kvv[k]   = kv;
    }

    float r = 0.f;
    if (m > -INFINITY) {          // at least one valid neighbor
        float s = 0.f, acc = 0.f;
#pragma unroll
        for (int k = 0; k < DEG; k++) {
            float p = __expf(logit[k] - m);  // padded: exp(-inf)=0
            s   += p;
            acc  = fmaf(p, kvv[k], acc);
        }
        r = acc / s;
    }
    // output layout [H][O][N]: row = lane, col = n
    out[(size_t)lane * N + n] = r;
}

extern "C" void kernel_launch(void* const* d_in, const int* in_sizes, int n_in,
                              void* d_out, int out_size, void* d_ws, size_t ws_size,
                              hipStream_t stream) {
    const int*   adj = (const int*)  d_in[0];
    const float* Q   = (const float*)d_in[1];
    const float* qw  = (const float*)d_in[2];
    const float* kw  = (const float*)d_in[3];
    const float* aw  = (const float*)d_in[4];
    float*       out = (float*)d_out;

    int N = in_sizes[0] / DEG;  // 50000

    float* Pq = (float*)d_ws;                 // [N][64]
    float* Pk = Pq + (size_t)N * NHO;         // [N][64]  (total 25.6 MB)

    dim3 pgrid((N + 255) / 256, 2);
    proj_kernel<<<pgrid, 256, 0, stream>>>(Q, qw, kw, Pq, Pk, N);

    gat_kernel<<<(N + 3) / 4, 256, 0, stream>>>(adj, Pq, Pk, aw, out, N);
}

// Round 2
// 210.895 us; speedup vs baseline: 1.2118x; 1.2118x over previous
//
#include <hip/hip_runtime.h>
#include <math.h>

#define DEG 32
#define IN_F 64
#define NHO 64   // HEADS*OUT_F = 4*16
#define NPW 8    // nodes per wave in gat_kernel
#define NPB 32   // nodes per block (4 waves * NPW)

// DPP butterfly add within rows of 16 lanes (one attention head).
// xor1 = quad_perm[1,0,3,2]=0xB1, xor2 = quad_perm[2,3,0,1]=0x4E,
// then row_half_mirror(0x141) acts as xor4 (quads already equal),
// row_mirror(0x140) acts as xor8 (halves already equal).
template <int CTRL>
__device__ __forceinline__ float dpp_add(float v) {
    int t = __builtin_amdgcn_update_dpp(0, __float_as_int(v), CTRL, 0xF, 0xF, true);
    return v + __int_as_float(t);
}

// ---------------------------------------------------------------------------
// Projection: P[n][l] = sum_i W[l][i] * Q[i][n], l = h*16+o in [0,64).
// Q column cached in 64 VGPRs; weight rows are wave-uniform -> scalar loads
// feeding v_fmac's SGPR operand. No LDS. blockIdx.y: 0 -> Pq, 1 -> Pk.
// ---------------------------------------------------------------------------
__global__ __launch_bounds__(256) void proj_kernel(
    const float* __restrict__ Q,
    const float* __restrict__ Wq,
    const float* __restrict__ Wk,
    float* __restrict__ Pq,
    float* __restrict__ Pk,
    int N)
{
    const float* W = (blockIdx.y == 0) ? Wq : Wk;
    float*       P = (blockIdx.y == 0) ? Pq : Pk;

    int n = blockIdx.x * 256 + threadIdx.x;
    if (n >= N) return;

    float q[IN_F];
#pragma unroll
    for (int i = 0; i < IN_F; i++) q[i] = Q[(size_t)i * N + n];  // coalesced

    for (int l4 = 0; l4 < 16; l4++) {
        float4 r;
#pragma unroll
        for (int u = 0; u < 4; u++) {
            const float* wr = W + (size_t)(l4 * 4 + u) * IN_F;  // wave-uniform
            float acc = 0.f;
#pragma unroll
            for (int i = 0; i < IN_F; i++) acc = fmaf(wr[i], q[i], acc);
            (&r.x)[u] = acc;
        }
        *(float4*)(P + (size_t)n * NHO + l4 * 4) = r;
    }
}

// ---------------------------------------------------------------------------
// GAT: one wave per node-batch (NPW nodes), lane = h*16+o.
// Per edge: scalar-broadcast neighbor id, coalesced 256B gather of Pk[j],
// leaky-relu, DPP reduction over the 16 o-lanes, online softmax update.
// Outputs staged in LDS so global writes are coalesced float4 along n.
// ---------------------------------------------------------------------------
__global__ __launch_bounds__(256) void gat_kernel(
    const int*   __restrict__ adj,   // [N][DEG]
    const float* __restrict__ Pq,    // [N][64]
    const float* __restrict__ Pk,    // [N][64]
    const float* __restrict__ aw,    // [64]
    float*       __restrict__ out,   // [64][N]
    int N)
{
    __shared__ float tile[NHO][NPB + 1];  // +1 pad: write banks (l+col)%32, 2-way = free

    int lane = threadIdx.x & 63;
    int wv   = threadIdx.x >> 6;

    // logits in log2 domain: fold log2(e) into the attention weight once
    float a2 = aw[lane] * 1.44269504f;

    int nbase = blockIdx.x * NPB + wv * NPW;

    for (int ni = 0; ni < NPW; ni++) {
        int n = nbase + ni;
        float r = 0.f;
        if (n < N) {
            float qv = Pq[(size_t)n * NHO + lane];
            int jreg = (lane < DEG) ? adj[(size_t)n * DEG + lane] : -1;

            float m = -1e30f, s = 0.f, acc = 0.f;
#pragma unroll
            for (int k = 0; k < DEG; k++) {
                int j      = __builtin_amdgcn_readlane(jreg, k);  // wave-uniform
                bool valid = (j >= 0);
                int  jc    = valid ? j : 0;
                float kv   = Pk[(size_t)jc * NHO + lane];  // coalesced 256B gather
                if (!valid) kv = 0.f;                      // uniform select

                float x = qv + kv;
                float c = a2 * fmaxf(x, 0.01f * x);        // leaky_relu * a*log2e
                // reduce over the 16 o-lanes of this head (DPP, VALU-only)
                c = dpp_add<0xB1>(c);    // xor 1
                c = dpp_add<0x4E>(c);    // xor 2
                c = dpp_add<0x141>(c);   // row_half_mirror == xor 4 here
                c = dpp_add<0x140>(c);   // row_mirror      == xor 8 here
                float lg = valid ? c : -1e30f;

                // online softmax (base-2 exponent domain)
                float nm = fmaxf(m, lg);
                float sc = exp2f(m - nm);
                float p  = exp2f(lg - nm);
                s   = fmaf(s, sc, p);
                acc = fmaf(acc, sc, p * kv);
                m   = nm;
            }
            // all-padded rows: s=DEG, acc=0 -> r=0 (matches reference)
            r = acc * __builtin_amdgcn_rcpf(s);
        }
        tile[lane][wv * NPW + ni] = r;
    }
    __syncthreads();

    // coalesced write-out: 64 rows x 32 cols = 512 float4, 2 per thread
    int n0 = blockIdx.x * NPB;
#pragma unroll
    for (int rnd = 0; rnd < 2; rnd++) {
        int idx = rnd * 256 + threadIdx.x;  // float4 index in [0,512)
        int l   = idx >> 3;                 // 8 float4 per row
        int c4  = idx & 7;
        int nc  = n0 + c4 * 4;
        float4 v = make_float4(tile[l][c4 * 4 + 0], tile[l][c4 * 4 + 1],
                               tile[l][c4 * 4 + 2], tile[l][c4 * 4 + 3]);
        if (nc + 3 < N) {
            *(float4*)(out + (size_t)l * N + nc) = v;
        } else {
#pragma unroll
            for (int e = 0; e < 4; e++)
                if (nc + e < N) out[(size_t)l * N + nc + e] = (&v.x)[e];
        }
    }
}

extern "C" void kernel_launch(void* const* d_in, const int* in_sizes, int n_in,
                              void* d_out, int out_size, void* d_ws, size_t ws_size,
                              hipStream_t stream) {
    const int*   adj = (const int*)  d_in[0];
    const float* Q   = (const float*)d_in[1];
    const float* qw  = (const float*)d_in[2];
    const float* kw  = (const float*)d_in[3];
    const float* aw  = (const float*)d_in[4];
    float*       out = (float*)d_out;

    int N = in_sizes[0] / DEG;  // 50000

    float* Pq = (float*)d_ws;                 // [N][64]
    float* Pk = Pq + (size_t)N * NHO;         // [N][64]

    dim3 pgrid((N + 255) / 256, 2);
    proj_kernel<<<pgrid, 256, 0, stream>>>(Q, qw, kw, Pq, Pk, N);

    gat_kernel<<<(N + NPB - 1) / NPB, 256, 0, stream>>>(adj, Pq, Pk, aw, out, N);
}

// Round 3
// 171.536 us; speedup vs baseline: 1.4899x; 1.2294x over previous
//
#include <hip/hip_runtime.h>
#include <math.h>

#define DEG 32
#define IN_F 64
#define NHO 64   // HEADS*OUT_F = 4*16
#define NPW 8    // nodes per wave in gat_kernel
#define NPB 32   // nodes per block (4 waves * NPW)
#define CH  16   // gather prefetch chunk (VGPRs for in-flight loads)

// DPP butterfly add within rows of 16 lanes (one attention head).
// xor1 = quad_perm[1,0,3,2]=0xB1, xor2 = quad_perm[2,3,0,1]=0x4E,
// then row_half_mirror(0x141) == xor4 (quads already uniform),
// row_mirror(0x140) == xor8 (halves already uniform).
template <int CTRL>
__device__ __forceinline__ float dpp_add(float v) {
    int t = __builtin_amdgcn_update_dpp(0, __float_as_int(v), CTRL, 0xF, 0xF, true);
    return v + __int_as_float(t);
}

// ---------------------------------------------------------------------------
// Projection: P[n][l] = sum_i W[l][i] * Q[i][n], l = h*16+o in [0,64).
// Weights staged transposed in LDS (float4-broadcast reads); Q column held in
// 64 VGPRs so the i-loop has no global-latency stalls. 128-thr blocks for
// better CU balance (782 blocks over 256 CUs).
// ---------------------------------------------------------------------------
__global__ __launch_bounds__(128) void proj_kernel(
    const float* __restrict__ Q,
    const float* __restrict__ Wq,
    const float* __restrict__ Wk,
    float* __restrict__ Pq,
    float* __restrict__ Pk,
    int N)
{
    __shared__ float wt[64 * 64];  // wt[i*64 + l] = W[l*64 + i]
    const float* W = (blockIdx.y == 0) ? Wq : Wk;
    float*       P = (blockIdx.y == 0) ? Pq : Pk;

    for (int idx = threadIdx.x; idx < 64 * 64; idx += 128) {
        int l = idx >> 6, i = idx & 63;
        wt[i * 64 + l] = W[idx];   // one-time; store conflicts are negligible
    }
    __syncthreads();

    int n = blockIdx.x * 128 + threadIdx.x;
    if (n >= N) return;

    float q[IN_F];
#pragma unroll
    for (int i = 0; i < IN_F; i++) q[i] = Q[(size_t)i * N + n];  // coalesced

    float acc[NHO];
#pragma unroll
    for (int l = 0; l < NHO; l++) acc[l] = 0.f;

    for (int i = 0; i < IN_F; i++) {
        float qv = q[i];
        const float4* w4 = (const float4*)&wt[i * 64];
#pragma unroll
        for (int l4 = 0; l4 < 16; l4++) {
            float4 w = w4[l4];  // LDS same-address broadcast
            acc[4 * l4 + 0] = fmaf(w.x, qv, acc[4 * l4 + 0]);
            acc[4 * l4 + 1] = fmaf(w.y, qv, acc[4 * l4 + 1]);
            acc[4 * l4 + 2] = fmaf(w.z, qv, acc[4 * l4 + 2]);
            acc[4 * l4 + 3] = fmaf(w.w, qv, acc[4 * l4 + 3]);
        }
    }

    float4* p4 = (float4*)&P[(size_t)n * NHO];
#pragma unroll
    for (int l4 = 0; l4 < 16; l4++)
        p4[l4] = make_float4(acc[4 * l4], acc[4 * l4 + 1],
                             acc[4 * l4 + 2], acc[4 * l4 + 3]);
}

// ---------------------------------------------------------------------------
// GAT: one wave handles NPW nodes, lane = h*16+o.
// Fixed-max softmax in exp2 domain (logits bounded << 127), so edges are
// fully independent -> 16-deep gather prefetch. Invalid edges annihilated
// by p = exp2(-1e30) = 0 (no kv select needed).
// ---------------------------------------------------------------------------
__global__ __launch_bounds__(256) void gat_kernel(
    const int*   __restrict__ adj,   // [N][DEG]
    const float* __restrict__ Pq,    // [N][64]
    const float* __restrict__ Pk,    // [N][64]
    const float* __restrict__ aw,    // [64]
    float*       __restrict__ out,   // [64][N]
    int N)
{
    __shared__ float tile[NHO][NPB + 1];

    int lane = threadIdx.x & 63;
    int wv   = threadIdx.x >> 6;

    float a2 = aw[lane] * 1.44269504f;  // fold log2(e) into attention weight

    int nbase = blockIdx.x * NPB + wv * NPW;

    for (int ni = 0; ni < NPW; ni++) {
        int n = nbase + ni;
        float r = 0.f;
        if (n < N) {
            float qv = Pq[(size_t)n * NHO + lane];
            int jreg = (lane < DEG) ? adj[(size_t)n * DEG + lane] : -1;

            float s = 0.f, acc = 0.f;
#pragma unroll
            for (int c = 0; c < DEG / CH; c++) {
                float kvb[CH];
                int   jb[CH];
#pragma unroll
                for (int t = 0; t < CH; t++) {
                    int j = __builtin_amdgcn_readlane(jreg, c * CH + t);  // SGPR
                    jb[t] = j;
                    const float* row = Pk + ((size_t)(j < 0 ? 0 : j) << 6);
                    kvb[t] = row[lane];   // coalesced 256B gather, SGPR base
                }
#pragma unroll
                for (int t = 0; t < CH; t++) {
                    float kv = kvb[t];
                    float x  = qv + kv;
                    float cc = a2 * fmaxf(x, 0.01f * x);  // leaky_relu * a*log2e
                    cc = dpp_add<0xB1>(cc);    // xor 1
                    cc = dpp_add<0x4E>(cc);    // xor 2
                    cc = dpp_add<0x141>(cc);   // xor 4 (half-mirror)
                    cc = dpp_add<0x140>(cc);   // xor 8 (mirror)
                    float lg = (jb[t] >= 0) ? cc : -1e30f;
                    float p  = __builtin_amdgcn_exp2f(lg);  // raw v_exp_f32
                    s   += p;
                    acc  = fmaf(p, kv, acc);
                }
            }
            // s==0 only when every neighbor is padded -> reference outputs 0
            r = (s > 0.f) ? acc * __builtin_amdgcn_rcpf(s) : 0.f;
        }
        tile[lane][wv * NPW + ni] = r;
    }
    __syncthreads();

    // coalesced write-out: 64 rows x 32 cols, float4 along n
    int n0 = blockIdx.x * NPB;
#pragma unroll
    for (int rnd = 0; rnd < 2; rnd++) {
        int idx = rnd * 256 + threadIdx.x;
        int l   = idx >> 3;
        int c4  = idx & 7;
        int nc  = n0 + c4 * 4;
        float4 v = make_float4(tile[l][c4 * 4 + 0], tile[l][c4 * 4 + 1],
                               tile[l][c4 * 4 + 2], tile[l][c4 * 4 + 3]);
        if (nc + 3 < N) {
            *(float4*)(out + (size_t)l * N + nc) = v;
        } else {
#pragma unroll
            for (int e = 0; e < 4; e++)
                if (nc + e < N) out[(size_t)l * N + nc + e] = (&v.x)[e];
        }
    }
}

extern "C" void kernel_launch(void* const* d_in, const int* in_sizes, int n_in,
                              void* d_out, int out_size, void* d_ws, size_t ws_size,
                              hipStream_t stream) {
    const int*   adj = (const int*)  d_in[0];
    const float* Q   = (const float*)d_in[1];
    const float* qw  = (const float*)d_in[2];
    const float* kw  = (const float*)d_in[3];
    const float* aw  = (const float*)d_in[4];
    float*       out = (float*)d_out;

    int N = in_sizes[0] / DEG;  // 50000

    float* Pq = (float*)d_ws;                 // [N][64]
    float* Pk = Pq + (size_t)N * NHO;         // [N][64]

    dim3 pgrid((N + 127) / 128, 2);
    proj_kernel<<<pgrid, 128, 0, stream>>>(Q, qw, kw, Pq, Pk, N);

    gat_kernel<<<(N + NPB - 1) / NPB, 256, 0, stream>>>(adj, Pq, Pk, aw, out, N);
}